// Round 11
// baseline (452.530 us; speedup 1.0000x reference)
//
#include <hip/hip_runtime.h>
#include <math.h>

#define N 8192
#define C 10
#define NUM_ITERS 5
#define FBLOCK 1024        /* 16 waves, 1 block/CU, 4 waves/SIMD, VGPR<=128 */
#define IBLK 32            /* i's per block */
#define NBLK (N / IBLK)    /* 256 blocks = 1 per CU */
#define JW (N / 16)        /* 512 j's per wave (contiguous slice) */
#define NS (JW / 32)       /* 16 s-iters per wave, 32 j's each */
#define LOG2E 1.44269504088896340736f
#define C3 (LOG2E / 64.0f)

typedef _Float16 half8 __attribute__((ext_vector_type(8)));
typedef _Float16 half4 __attribute__((ext_vector_type(4)));
typedef _Float16 half2 __attribute__((ext_vector_type(2)));
typedef float f32x4 __attribute__((ext_vector_type(4)));

// ws layout:
//   ajs half8[N]        128KB : j-side spatial aug [f*C3 x3, 0, 0,0,-h3*C3, 1]
//   ajb half8[N]        128KB : j-side bilateral aug [f*L2E x6, -h6*L2E, 1]
//   pf0 f16[N/16][16][16] 256KB : probs, J-TILED; rows 10..15 zero
//   pf1 f16[N/16][16][16] 256KB : ping-pong partner
//   scrap (2MB+)              : probe-kernel sinks (no overlap with pipeline)
#define WS_AJS 0
#define WS_AJB (N * 16)
#define WS_PF0 (N * 32)
#define WS_PF1 (N * 64)
#define WS_SCRAP (2 * 1024 * 1024)
#define PFIDX(n, c) ((((n) >> 4) * 16 + (c)) * 16 + ((n) & 15))

static __device__ __forceinline__ half4 expcvt(f32x4 d) {
    float e0 = __builtin_amdgcn_exp2f(d[0]);
    float e1 = __builtin_amdgcn_exp2f(d[1]);
    float e2 = __builtin_amdgcn_exp2f(d[2]);
    float e3 = __builtin_amdgcn_exp2f(d[3]);
    half2 lo = __builtin_bit_cast(half2, __builtin_amdgcn_cvt_pkrtz(e0, e1));
    half2 hi = __builtin_bit_cast(half2, __builtin_amdgcn_cvt_pkrtz(e2, e3));
    half4 r = {lo[0], lo[1], hi[0], hi[1]};
    return r;
}

struct Ops { half4 vs0, vs1, vb0, vb1, p0, p1; };
struct Dset { f32x4 d0, d1, d2, d3, d4, d5, d6, d7; };

// once per launch: aug features + softmax(unaries) -> pf0 (tiled); zero rows 10..15 both
__global__ __launch_bounds__(256) void init_kernel(
    const float* __restrict__ unaries, const float* __restrict__ feat,
    half8* __restrict__ ajs8, half8* __restrict__ ajb8,
    _Float16* __restrict__ pf0, _Float16* __restrict__ pf1) {
    int n = blockIdx.x * 256 + threadIdx.x;
    float f6[6];
#pragma unroll
    for (int d = 0; d < 6; ++d) f6[d] = feat[d * N + n];
    float h3 = 0.5f * (f6[0] * f6[0] + f6[1] * f6[1] + f6[2] * f6[2]);
    float h6v = h3 + 0.5f * (f6[3] * f6[3] + f6[4] * f6[4] + f6[5] * f6[5]);
    half8 a = {};
    a[0] = (_Float16)(f6[0] * C3);
    a[1] = (_Float16)(f6[1] * C3);
    a[2] = (_Float16)(f6[2] * C3);
    a[6] = (_Float16)(-h3 * C3);
    a[7] = (_Float16)1.0f;
    ajs8[n] = a;
    half8 b;
#pragma unroll
    for (int d = 0; d < 6; ++d) b[d] = (_Float16)(f6[d] * LOG2E);
    b[6] = (_Float16)(-h6v * LOG2E);
    b[7] = (_Float16)1.0f;
    ajb8[n] = b;

    float q[C];
#pragma unroll
    for (int c = 0; c < C; ++c) q[c] = unaries[c * N + n];
    float m = q[0];
#pragma unroll
    for (int c = 1; c < C; ++c) m = fmaxf(m, q[c]);
    float e[C], s = 0.0f;
#pragma unroll
    for (int c = 0; c < C; ++c) {
        e[c] = __builtin_amdgcn_exp2f((q[c] - m) * LOG2E);
        s += e[c];
    }
    float inv = 1.0f / s;
#pragma unroll
    for (int c = 0; c < C; ++c) pf0[PFIDX(n, c)] = (_Float16)(e[c] * inv);
#pragma unroll
    for (int c = C; c < 16; ++c) {
        pf0[PFIDX(n, c)] = (_Float16)0.0f;
        pf1[PFIDX(n, c)] = (_Float16)0.0f;
    }
}

// ============================ champion pipeline (R10) ============================
__global__ __launch_bounds__(FBLOCK, 4) void fused_kernel(
    const float* __restrict__ unaries, const float* __restrict__ feat,
    const float* __restrict__ SW, const float* __restrict__ BW,
    const float* __restrict__ CM,
    const half4* __restrict__ ajs_g, const half4* __restrict__ ajb_g,
    const _Float16* __restrict__ pf_in, _Float16* __restrict__ pf_out,
    float* __restrict__ out, int is_last) {
    __shared__ float rbuf[16 * 1024];   // 64 KB, epilogue only
    int t = threadIdx.x;
    int i0 = blockIdx.x * IBLK;
    int lane = t & 63;
    int w = t >> 6;
    int il = lane & 15;
    int quad = lane >> 4;
    int h = quad & 1;
    bool klo = (quad < 2);
    const half4 hz = {};
    const f32x4 zero = {0.f, 0.f, 0.f, 0.f};

    half4 b1s0, b1s1, b1b0, b1b1;
#pragma unroll
    for (int s = 0; s < 2; ++s) {
        int i = i0 + s * 16 + il;
        float g0 = feat[0 * N + i], g1 = feat[1 * N + i], g2 = feat[2 * N + i];
        float g3 = feat[3 * N + i], g4 = feat[4 * N + i], g5 = feat[5 * N + i];
        float h3 = 0.5f * (g0 * g0 + g1 * g1 + g2 * g2);
        float h6v = h3 + 0.5f * (g3 * g3 + g4 * g4 + g5 * g5);
        half4 slo = {(_Float16)g0, (_Float16)g1, (_Float16)g2, (_Float16)0.0f};
        half4 shi = {(_Float16)0.0f, (_Float16)0.0f, (_Float16)1.0f, (_Float16)(-h3 * C3)};
        half4 blo = {(_Float16)g0, (_Float16)g1, (_Float16)g2, (_Float16)g3};
        half4 bhi = {(_Float16)g4, (_Float16)g5, (_Float16)1.0f, (_Float16)(-h6v * LOG2E)};
        half4 vs = klo ? (h ? shi : slo) : hz;
        half4 vb = klo ? (h ? bhi : blo) : hz;
        if (s == 0) { b1s0 = vs; b1b0 = vb; } else { b1s1 = vs; b1b1 = vb; }
    }

    f32x4 as0 = zero, as1 = zero, ab0 = zero, ab1 = zero;
    int jw = w * JW;
    const half4* pfv = (const half4*)pf_in;

#define LOAD_OPS(O, K)                                                     \
    {                                                                      \
        int _j0 = jw + ((K) & (NS - 1)) * 32;                              \
        O.vs0 = ajs_g[(_j0 + il) * 2 + h];                                 \
        O.vs1 = ajs_g[(_j0 + 16 + il) * 2 + h];                            \
        O.vb0 = ajb_g[(_j0 + il) * 2 + h];                                 \
        O.vb1 = ajb_g[(_j0 + 16 + il) * 2 + h];                            \
        O.p0 = pfv[((_j0 >> 4) * 16 + il) * 4 + quad];                     \
        O.p1 = pfv[(((_j0 >> 4) + 1) * 16 + il) * 4 + quad];               \
    }
#define G1(D, O)                                                               \
    {                                                                          \
        D.d0 = __builtin_amdgcn_mfma_f32_16x16x16f16(O.vs0, b1s0, zero, 0, 0, 0); \
        D.d1 = __builtin_amdgcn_mfma_f32_16x16x16f16(O.vs0, b1s1, zero, 0, 0, 0); \
        D.d2 = __builtin_amdgcn_mfma_f32_16x16x16f16(O.vs1, b1s0, zero, 0, 0, 0); \
        D.d3 = __builtin_amdgcn_mfma_f32_16x16x16f16(O.vs1, b1s1, zero, 0, 0, 0); \
        D.d4 = __builtin_amdgcn_mfma_f32_16x16x16f16(O.vb0, b1b0, zero, 0, 0, 0); \
        D.d5 = __builtin_amdgcn_mfma_f32_16x16x16f16(O.vb0, b1b1, zero, 0, 0, 0); \
        D.d6 = __builtin_amdgcn_mfma_f32_16x16x16f16(O.vb1, b1b0, zero, 0, 0, 0); \
        D.d7 = __builtin_amdgcn_mfma_f32_16x16x16f16(O.vb1, b1b1, zero, 0, 0, 0); \
    }
#define G2(D, O)                                                               \
    {                                                                          \
        half4 _w0 = expcvt(D.d0), _w1 = expcvt(D.d1);                          \
        half4 _w2 = expcvt(D.d2), _w3 = expcvt(D.d3);                          \
        half4 _w4 = expcvt(D.d4), _w5 = expcvt(D.d5);                          \
        half4 _w6 = expcvt(D.d6), _w7 = expcvt(D.d7);                          \
        as0 = __builtin_amdgcn_mfma_f32_16x16x16f16(_w0, O.p0, as0, 0, 0, 0);  \
        as1 = __builtin_amdgcn_mfma_f32_16x16x16f16(_w1, O.p0, as1, 0, 0, 0);  \
        as0 = __builtin_amdgcn_mfma_f32_16x16x16f16(_w2, O.p1, as0, 0, 0, 0);  \
        as1 = __builtin_amdgcn_mfma_f32_16x16x16f16(_w3, O.p1, as1, 0, 0, 0);  \
        ab0 = __builtin_amdgcn_mfma_f32_16x16x16f16(_w4, O.p0, ab0, 0, 0, 0);  \
        ab1 = __builtin_amdgcn_mfma_f32_16x16x16f16(_w5, O.p0, ab1, 0, 0, 0);  \
        ab0 = __builtin_amdgcn_mfma_f32_16x16x16f16(_w6, O.p1, ab0, 0, 0, 0);  \
        ab1 = __builtin_amdgcn_mfma_f32_16x16x16f16(_w7, O.p1, ab1, 0, 0, 0);  \
    }

    Ops opA, opB;
    Dset dd;
    LOAD_OPS(opA, 0);
    LOAD_OPS(opB, 1);
    G1(dd, opA);
    for (int m = 0; m < 7; ++m) {
        G2(dd, opA);
        LOAD_OPS(opA, 2 * m + 2);
        G1(dd, opB);
        G2(dd, opB);
        LOAD_OPS(opB, 2 * m + 3);
        G1(dd, opA);
    }
    G2(dd, opA);
    G1(dd, opB);
    G2(dd, opB);
#undef LOAD_OPS
#undef G1
#undef G2

    {
        float* rb = rbuf + w * 1024;
#pragma unroll
        for (int r = 0; r < 4; ++r) {
            rb[r * 64 + lane]       = as0[r];
            rb[256 + r * 64 + lane] = as1[r];
            rb[512 + r * 64 + lane] = ab0[r];
            rb[768 + r * 64 + lane] = ab1[r];
        }
    }
    __syncthreads();
    {
        float tot = 0.f;
#pragma unroll
        for (int w2 = 0; w2 < 16; ++w2) tot += rbuf[w2 * 1024 + t];
        rbuf[t] = tot;
    }
    __syncthreads();

    if (t < IBLK) {
        int i = i0 + t;
        int sub = t >> 4, ql = (t & 15) >> 2, rr = t & 3;
        float sp[C], bl[C];
#pragma unroll
        for (int c = 0; c < C; ++c) {
            int base = sub * 256 + rr * 64 + ql * 16 + c;
            sp[c] = rbuf[base];
            bl[c] = rbuf[base + 512];
        }
        float msg[C];
#pragma unroll
        for (int c = 0; c < C; ++c) {
            float m = 0.f;
#pragma unroll
            for (int k = 0; k < C; ++k)
                m += SW[c * C + k] * sp[k] + BW[c * C + k] * bl[k];
            msg[c] = m;
        }
        float qq[C];
#pragma unroll
        for (int c = 0; c < C; ++c) {
            float pw = 0.f;
#pragma unroll
            for (int k = 0; k < C; ++k) pw += CM[c * C + k] * msg[k];
            qq[c] = unaries[c * N + i] - pw;
        }
        if (is_last) {
#pragma unroll
            for (int c = 0; c < C; ++c) out[c * N + i] = qq[c];
        } else {
            float m = qq[0];
#pragma unroll
            for (int c = 1; c < C; ++c) m = fmaxf(m, qq[c]);
            float e[C], s = 0.0f;
#pragma unroll
            for (int c = 0; c < C; ++c) {
                e[c] = __builtin_amdgcn_exp2f((qq[c] - m) * LOG2E);
                s += e[c];
            }
            float inv = 1.0f / s;
#pragma unroll
            for (int c = 0; c < C; ++c) pf_out[PFIDX(i, c)] = (_Float16)(e[c] * inv);
        }
    }
}

// ====================== diagnostic probes (scrap-only, run after pipeline) ======================

// PROBE 1: pure trans-pipe. 8 independent exp2 chains x 768 = 6144 exp2/thread
// = 12 iteration-equivalents of the real exp workload.
__global__ __launch_bounds__(1024, 4) void probe_exp(const float* __restrict__ src,
                                                     float* __restrict__ dst) {
    int tid = blockIdx.x * 1024 + threadIdx.x;
    float x0 = src[tid & 8191], x1 = src[(tid + 1) & 8191];
    float x2 = src[(tid + 2) & 8191], x3 = src[(tid + 3) & 8191];
    float x4 = src[(tid + 4) & 8191], x5 = src[(tid + 5) & 8191];
    float x6 = src[(tid + 6) & 8191], x7 = src[(tid + 7) & 8191];
    for (int k = 0; k < 768; ++k) {
        x0 = __builtin_amdgcn_exp2f(x0);
        x1 = __builtin_amdgcn_exp2f(x1);
        x2 = __builtin_amdgcn_exp2f(x2);
        x3 = __builtin_amdgcn_exp2f(x3);
        x4 = __builtin_amdgcn_exp2f(x4);
        x5 = __builtin_amdgcn_exp2f(x5);
        x6 = __builtin_amdgcn_exp2f(x6);
        x7 = __builtin_amdgcn_exp2f(x7);
    }
    dst[tid] = x0 + x1 + x2 + x3 + x4 + x5 + x6 + x7;
}

// PROBE 2: loads + GEMM1 stream only (no exp, no GEMM2), 24 duty sweeps.
// Measures MFMA throughput with the real load pattern overlapped.
__global__ __launch_bounds__(1024, 4) void probe_mfma(
    const half4* __restrict__ ajs_g, const half4* __restrict__ ajb_g,
    const _Float16* __restrict__ pf_in, float* __restrict__ dst) {
    int t = threadIdx.x;
    int lane = t & 63;
    int w = t >> 6;
    int il = lane & 15;
    int quad = lane >> 4;
    int h = quad & 1;
    const f32x4 zero = {0.f, 0.f, 0.f, 0.f};
    int jw = w * JW;

    half4 b1s0 = ajb_g[il * 2], b1s1 = ajb_g[il * 2 + 1];
    half4 b1b0 = ajb_g[32 + il * 2], b1b1 = ajb_g[32 + il * 2 + 1];

    float keep = 0.f;
    for (int d = 0; d < 24; ++d) {
        const half4* as_ = ajs_g + (d & 1);   // defeat cross-duty CSE/hoist
        const half4* ab_ = ajb_g + (d & 1);
        const half4* pv_ = (const half4*)pf_in + (d & 1);
        Dset dd;
        for (int k = 0; k < NS; ++k) {
            int j0 = jw + k * 32;
            Ops o;
            o.vs0 = as_[(j0 + il) * 2 + h];
            o.vs1 = as_[(j0 + 16 + il) * 2 + h];
            o.vb0 = ab_[(j0 + il) * 2 + h];
            o.vb1 = ab_[(j0 + 16 + il) * 2 + h];
            o.p0 = pv_[((j0 >> 4) * 16 + il) * 4 + quad];
            o.p1 = pv_[(((j0 >> 4) + 1) * 16 + il) * 4 + quad];
            dd.d0 = __builtin_amdgcn_mfma_f32_16x16x16f16(o.vs0, b1s0, zero, 0, 0, 0);
            dd.d1 = __builtin_amdgcn_mfma_f32_16x16x16f16(o.vs0, b1s1, zero, 0, 0, 0);
            dd.d2 = __builtin_amdgcn_mfma_f32_16x16x16f16(o.vs1, b1s0, zero, 0, 0, 0);
            dd.d3 = __builtin_amdgcn_mfma_f32_16x16x16f16(o.vs1, b1s1, zero, 0, 0, 0);
            dd.d4 = __builtin_amdgcn_mfma_f32_16x16x16f16(o.vb0, b1b0, zero, 0, 0, 0);
            dd.d5 = __builtin_amdgcn_mfma_f32_16x16x16f16(o.vb0, b1b1, zero, 0, 0, 0);
            dd.d6 = __builtin_amdgcn_mfma_f32_16x16x16f16(o.vb1, b1b0, zero, 0, 0, 0);
            dd.d7 = __builtin_amdgcn_mfma_f32_16x16x16f16(o.vb1, b1b1, zero, 0, 0, 0);
            // keep-alive: conditional store the compiler cannot prove dead
            if ((int)(blockIdx.x * 1024u + (unsigned)t) == 999999) {
                keep += dd.d0[0] + dd.d1[1] + dd.d2[2] + dd.d3[3] +
                        dd.d4[0] + dd.d5[1] + dd.d6[2] + dd.d7[3] +
                        (float)o.p0[0] + (float)o.p1[0];
            }
        }
    }
    if ((int)(blockIdx.x * 1024u + (unsigned)t) == 999999) dst[0] = keep;
}

// PROBE 3: the full filter loop (loads + GEMM1 + exp + GEMM2), duty 2.
// Proxy for the real fused kernel's main loop, sized >39.5us for top-5 visibility.
__global__ __launch_bounds__(1024, 4) void probe_filter(
    const half4* __restrict__ ajs_g, const half4* __restrict__ ajb_g,
    const _Float16* __restrict__ pf_in, float* __restrict__ dst) {
    int t = threadIdx.x;
    int lane = t & 63;
    int w = t >> 6;
    int il = lane & 15;
    int quad = lane >> 4;
    int h = quad & 1;
    const f32x4 zero = {0.f, 0.f, 0.f, 0.f};
    int jw = w * JW;

    half4 b1s0 = ajb_g[il * 2], b1s1 = ajb_g[il * 2 + 1];
    half4 b1b0 = ajb_g[32 + il * 2], b1b1 = ajb_g[32 + il * 2 + 1];
    f32x4 as0 = zero, as1 = zero, ab0 = zero, ab1 = zero;

    for (int d = 0; d < 2; ++d) {
        const half4* as_ = ajs_g + (d & 1);
        const half4* ab_ = ajb_g + (d & 1);
        const half4* pv_ = (const half4*)pf_in + (d & 1);
        for (int k = 0; k < NS; ++k) {
            int j0 = jw + k * 32;
            Ops o;
            o.vs0 = as_[(j0 + il) * 2 + h];
            o.vs1 = as_[(j0 + 16 + il) * 2 + h];
            o.vb0 = ab_[(j0 + il) * 2 + h];
            o.vb1 = ab_[(j0 + 16 + il) * 2 + h];
            o.p0 = pv_[((j0 >> 4) * 16 + il) * 4 + quad];
            o.p1 = pv_[(((j0 >> 4) + 1) * 16 + il) * 4 + quad];
            Dset dd;
            dd.d0 = __builtin_amdgcn_mfma_f32_16x16x16f16(o.vs0, b1s0, zero, 0, 0, 0);
            dd.d1 = __builtin_amdgcn_mfma_f32_16x16x16f16(o.vs0, b1s1, zero, 0, 0, 0);
            dd.d2 = __builtin_amdgcn_mfma_f32_16x16x16f16(o.vs1, b1s0, zero, 0, 0, 0);
            dd.d3 = __builtin_amdgcn_mfma_f32_16x16x16f16(o.vs1, b1s1, zero, 0, 0, 0);
            dd.d4 = __builtin_amdgcn_mfma_f32_16x16x16f16(o.vb0, b1b0, zero, 0, 0, 0);
            dd.d5 = __builtin_amdgcn_mfma_f32_16x16x16f16(o.vb0, b1b1, zero, 0, 0, 0);
            dd.d6 = __builtin_amdgcn_mfma_f32_16x16x16f16(o.vb1, b1b0, zero, 0, 0, 0);
            dd.d7 = __builtin_amdgcn_mfma_f32_16x16x16f16(o.vb1, b1b1, zero, 0, 0, 0);
            half4 w0 = expcvt(dd.d0), w1 = expcvt(dd.d1);
            half4 w2 = expcvt(dd.d2), w3 = expcvt(dd.d3);
            half4 w4 = expcvt(dd.d4), w5 = expcvt(dd.d5);
            half4 w6 = expcvt(dd.d6), w7 = expcvt(dd.d7);
            as0 = __builtin_amdgcn_mfma_f32_16x16x16f16(w0, o.p0, as0, 0, 0, 0);
            as1 = __builtin_amdgcn_mfma_f32_16x16x16f16(w1, o.p0, as1, 0, 0, 0);
            as0 = __builtin_amdgcn_mfma_f32_16x16x16f16(w2, o.p1, as0, 0, 0, 0);
            as1 = __builtin_amdgcn_mfma_f32_16x16x16f16(w3, o.p1, as1, 0, 0, 0);
            ab0 = __builtin_amdgcn_mfma_f32_16x16x16f16(w4, o.p0, ab0, 0, 0, 0);
            ab1 = __builtin_amdgcn_mfma_f32_16x16x16f16(w5, o.p0, ab1, 0, 0, 0);
            ab0 = __builtin_amdgcn_mfma_f32_16x16x16f16(w6, o.p1, ab0, 0, 0, 0);
            ab1 = __builtin_amdgcn_mfma_f32_16x16x16f16(w7, o.p1, ab1, 0, 0, 0);
        }
    }
    float* dv = dst + ((size_t)blockIdx.x * 1024 + t) * 4;
    dv[0] = as0[0] + as1[1];
    dv[1] = ab0[2] + ab1[3];
    dv[2] = as0[2] + ab1[0];
    dv[3] = as1[3] + ab0[1];
}

extern "C" void kernel_launch(void* const* d_in, const int* in_sizes, int n_in,
                              void* d_out, int out_size, void* d_ws, size_t ws_size,
                              hipStream_t stream) {
    const float* unaries = (const float*)d_in[0];   // [10, 8192]
    const float* feat    = (const float*)d_in[1];   // [6, 8192]
    const float* SW      = (const float*)d_in[2];   // [10,10]
    const float* BW      = (const float*)d_in[3];   // [10,10]
    const float* CM      = (const float*)d_in[4];   // [10,10]
    float* out = (float*)d_out;

    char* ws = (char*)d_ws;
    half8* ajs    = (half8*)(ws + WS_AJS);
    half8* ajb    = (half8*)(ws + WS_AJB);
    _Float16* pf0 = (_Float16*)(ws + WS_PF0);
    _Float16* pf1 = (_Float16*)(ws + WS_PF1);
    float* scrap  = (float*)(ws + WS_SCRAP);

    init_kernel<<<N / 256, 256, 0, stream>>>(unaries, feat, ajs, ajb, pf0, pf1);
    const _Float16* pin = pf0;
    _Float16* pout = pf1;
    for (int it = 1; it <= NUM_ITERS; ++it) {
        fused_kernel<<<NBLK, FBLOCK, 0, stream>>>(
            unaries, feat, SW, BW, CM, (const half4*)ajs, (const half4*)ajb,
            pin, pout, out, it == NUM_ITERS ? 1 : 0);
        const _Float16* tmp = pout;
        pout = (_Float16*)pin;
        pin = tmp;
    }
    // -------- diagnostic probes (scrap-only; do not touch pipeline state) --------
    probe_exp<<<NBLK, FBLOCK, 0, stream>>>(unaries, scrap);
    probe_mfma<<<NBLK, FBLOCK, 0, stream>>>((const half4*)ajs, (const half4*)ajb,
                                            pf0, scrap + 512 * 1024);
    probe_filter<<<NBLK, FBLOCK, 0, stream>>>((const half4*)ajs, (const half4*)ajb,
                                              pf0, scrap + 1024 * 1024);
}

// Round 12
// 165.067 us; speedup vs baseline: 2.7415x; 2.7415x over previous
//
#include <hip/hip_runtime.h>
#include <math.h>

#define N 8192
#define C 10
#define NUM_ITERS 5
#define FBLOCK 1024        /* 16 waves, 1 block/CU, 4 waves/SIMD */
#define IBLK 32            /* i's per block */
#define NBLK (N / IBLK)    /* 256 blocks = 1 per CU */
#define JW (N / 16)        /* 512 j's per wave */
#define NS (JW / 32)       /* 16 s-iters per wave, 32 j's each */
#define LOG2E 1.44269504088896340736f
#define C3 (LOG2E / 64.0f)

typedef _Float16 half8 __attribute__((ext_vector_type(8)));
typedef _Float16 half4 __attribute__((ext_vector_type(4)));
typedef _Float16 half2 __attribute__((ext_vector_type(2)));
typedef float f32x4 __attribute__((ext_vector_type(4)));
typedef float f32x16 __attribute__((ext_vector_type(16)));

// ws layout:
//   ajs half8[N]          128KB : j-side spatial aug [f*C3 x3, 0 | 0,0,-h3*C3, 1]
//   ajb half8[N]          128KB : j-side bilateral aug [f*L2E x6 | -h6*L2E, 1]
//   pf0/pf1 f16[N/16][16][16]   : probs, J-TILED (tile jt, row c, col j&15)
#define WS_AJS 0
#define WS_AJB (N * 16)
#define WS_PF0 (N * 32)
#define WS_PF1 (N * 64)
#define PFIDX(n, c) ((((n) >> 4) * 16 + (c)) * 16 + ((n) & 15))

static __device__ __forceinline__ unsigned int pkexp(float a, float b) {
    float ea = __builtin_amdgcn_exp2f(a);
    float eb = __builtin_amdgcn_exp2f(b);
    return __builtin_bit_cast(unsigned int, __builtin_amdgcn_cvt_pkrtz(ea, eb));
}

// read one G2 A-fragment from the per-wave transpose tile:
// elems e0..3 = w[i][4q..4q+3] (u32 cols 2q,2q+1), e4..7 = w[i][16+4q..] (cols 8+2q,..)
static __device__ __forceinline__ half8 rdfrag(const unsigned int* R, int q) {
    uint2 lo = *(const uint2*)&R[2 * q];
    uint2 hi = *(const uint2*)&R[8 + 2 * q];
    half2 a = __builtin_bit_cast(half2, lo.x);
    half2 b = __builtin_bit_cast(half2, lo.y);
    half2 c = __builtin_bit_cast(half2, hi.x);
    half2 d = __builtin_bit_cast(half2, hi.y);
    half8 r = {a[0], a[1], b[0], b[1], c[0], c[1], d[0], d[1]};
    return r;
}

// once per launch: aug features + softmax(unaries) -> pf0 (tiled); zero rows 10..15 both
__global__ __launch_bounds__(256) void init_kernel(
    const float* __restrict__ unaries, const float* __restrict__ feat,
    half8* __restrict__ ajs8, half8* __restrict__ ajb8,
    _Float16* __restrict__ pf0, _Float16* __restrict__ pf1) {
    int n = blockIdx.x * 256 + threadIdx.x;
    float f6[6];
#pragma unroll
    for (int d = 0; d < 6; ++d) f6[d] = feat[d * N + n];
    float h3 = 0.5f * (f6[0] * f6[0] + f6[1] * f6[1] + f6[2] * f6[2]);
    float h6v = h3 + 0.5f * (f6[3] * f6[3] + f6[4] * f6[4] + f6[5] * f6[5]);
    half8 a = {};
    a[0] = (_Float16)(f6[0] * C3);
    a[1] = (_Float16)(f6[1] * C3);
    a[2] = (_Float16)(f6[2] * C3);
    a[6] = (_Float16)(-h3 * C3);
    a[7] = (_Float16)1.0f;
    ajs8[n] = a;
    half8 b;
#pragma unroll
    for (int d = 0; d < 6; ++d) b[d] = (_Float16)(f6[d] * LOG2E);
    b[6] = (_Float16)(-h6v * LOG2E);
    b[7] = (_Float16)1.0f;
    ajb8[n] = b;

    float q[C];
#pragma unroll
    for (int c = 0; c < C; ++c) q[c] = unaries[c * N + n];
    float m = q[0];
#pragma unroll
    for (int c = 1; c < C; ++c) m = fmaxf(m, q[c]);
    float e[C], s = 0.0f;
#pragma unroll
    for (int c = 0; c < C; ++c) {
        e[c] = __builtin_amdgcn_exp2f((q[c] - m) * LOG2E);
        s += e[c];
    }
    float inv = 1.0f / s;
#pragma unroll
    for (int c = 0; c < C; ++c) pf0[PFIDX(n, c)] = (_Float16)(e[c] * inv);
#pragma unroll
    for (int c = C; c < 16; ++c) {
        pf0[PFIDX(n, c)] = (_Float16)0.0f;
        pf1[PFIDX(n, c)] = (_Float16)0.0f;
    }
}

// one dispatch per CRF iteration. Block owns 32 i's; wave sweeps its 512-j slice.
// Per s-iter: GEMM1 = 2x mfma_32x32x16_f16 (one per filter, K=16 >= aug8);
// exp+cvt_pk -> per-wave LDS transpose tile (stride-18 u32 rows, <=2-way banks);
// GEMM2 = 4x mfma_16x16x32_f16 (K=32 = all 32 j's). ~2.1x less MFMA pipe time
// than the 16x16x16 version (legacy K=16 shape costs a full pipe slot).
__global__ __launch_bounds__(FBLOCK, 4) void fused_kernel(
    const float* __restrict__ unaries, const float* __restrict__ feat,
    const float* __restrict__ SW, const float* __restrict__ BW,
    const float* __restrict__ CM,
    const char* __restrict__ ajs_c, const char* __restrict__ ajb_c,
    const _Float16* __restrict__ pf_in, _Float16* __restrict__ pf_out,
    float* __restrict__ out, int is_last) {
    __shared__ union {
        unsigned int wt[16][2][32][18];   // 73,728 B: per-wave w-tiles [wave][filter][i][u32 col]
        float rbuf[16 * 1024];            // 64 KB epilogue reduction (after barrier)
    } sm;
    int t = threadIdx.x;
    int i0 = blockIdx.x * IBLK;
    int lane = t & 63;
    int w = t >> 6;
    int il = lane & 15;
    int quad = lane >> 4;
    int li = lane & 31;      // i (B1/G1-D col) or j (G1-A row) within 32
    int hs = lane >> 5;      // K-half select for 32x32x16 operands
    const f32x4 zero4 = {0.f, 0.f, 0.f, 0.f};
    const f32x16 zero16 = {};

    // ---- B1 fragments (G1 B-operand): lane holds aug[4hs..4hs+3] of i=i0+li ----
    half8 b1s, b1b;
    {
        int i = i0 + li;
        float g0 = feat[0 * N + i], g1 = feat[1 * N + i], g2 = feat[2 * N + i];
        float g3 = feat[3 * N + i], g4 = feat[4 * N + i], g5 = feat[5 * N + i];
        float h3 = 0.5f * (g0 * g0 + g1 * g1 + g2 * g2);
        float h6v = h3 + 0.5f * (g3 * g3 + g4 * g4 + g5 * g5);
        half4 slo = {(_Float16)g0, (_Float16)g1, (_Float16)g2, (_Float16)0.0f};
        half4 shi = {(_Float16)0.0f, (_Float16)0.0f, (_Float16)1.0f, (_Float16)(-h3 * C3)};
        half4 blo = {(_Float16)g0, (_Float16)g1, (_Float16)g2, (_Float16)g3};
        half4 bhi = {(_Float16)g4, (_Float16)g5, (_Float16)1.0f, (_Float16)(-h6v * LOG2E)};
        half4 sv = hs ? shi : slo;
        half4 bv = hs ? bhi : blo;
        half8 t1 = {sv[0], sv[1], sv[2], sv[3], (_Float16)0.0f, (_Float16)0.0f,
                    (_Float16)0.0f, (_Float16)0.0f};
        half8 t2 = {bv[0], bv[1], bv[2], bv[3], (_Float16)0.0f, (_Float16)0.0f,
                    (_Float16)0.0f, (_Float16)0.0f};
        b1s = t1;
        b1b = t2;
    }

    f32x4 as0 = zero4, as1 = zero4, ab0 = zero4, ab1 = zero4;
    int jw = w * JW;
    const half4* pfv = (const half4*)pf_in;
    unsigned int* Ws = &sm.wt[w][0][li][0];
    unsigned int* Wb = &sm.wt[w][1][li][0];
    const unsigned int* R0s = &sm.wt[w][0][il][0];
    const unsigned int* R1s = &sm.wt[w][0][16 + il][0];
    const unsigned int* R0b = &sm.wt[w][1][il][0];
    const unsigned int* R1b = &sm.wt[w][1][16 + il][0];

    for (int k = 0; k < NS; ++k) {
        int j0 = jw + k * 32;
        // G1 A-operand: aug[4hs..4hs+3] of j = j0+li (half of the stored half8)
        half4 av_s = *(const half4*)(ajs_c + (size_t)(j0 + li) * 16 + hs * 8);
        half4 av_b = *(const half4*)(ajb_c + (size_t)(j0 + li) * 16 + hs * 8);
        // G2 B-operand: p[c=il][j0 + 4q+0..3] and [j0+16+4q+0..3] (two K-halves)
        half4 cp0 = pfv[((j0 >> 4) * 16 + il) * 4 + quad];
        half4 cp1 = pfv[(((j0 >> 4) + 1) * 16 + il) * 4 + quad];
        half8 A_s = {av_s[0], av_s[1], av_s[2], av_s[3], (_Float16)0.0f,
                     (_Float16)0.0f, (_Float16)0.0f, (_Float16)0.0f};
        half8 A_b = {av_b[0], av_b[1], av_b[2], av_b[3], (_Float16)0.0f,
                     (_Float16)0.0f, (_Float16)0.0f, (_Float16)0.0f};
        half8 Bp = {cp0[0], cp0[1], cp0[2], cp0[3], cp1[0], cp1[1], cp1[2], cp1[3]};

        // GEMM-1: D1[j][i] (col=lane&31=i, row j=(r&3)+8*(r>>2)+4*hs), one per filter
        f32x16 d1s = __builtin_amdgcn_mfma_f32_32x32x16_f16(A_s, b1s, zero16, 0, 0, 0);
        f32x16 d1b = __builtin_amdgcn_mfma_f32_32x32x16_f16(A_b, b1b, zero16, 0, 0, 0);

        // exp2 + pack to f16-pairs (adjacent j) + transpose-store rows [i][j]
        {
            uint2 v;
            v.x = pkexp(d1s[0], d1s[1]);  v.y = pkexp(d1s[2], d1s[3]);
            *(uint2*)&Ws[0 + 2 * hs] = v;
            v.x = pkexp(d1s[4], d1s[5]);  v.y = pkexp(d1s[6], d1s[7]);
            *(uint2*)&Ws[4 + 2 * hs] = v;
            v.x = pkexp(d1s[8], d1s[9]);  v.y = pkexp(d1s[10], d1s[11]);
            *(uint2*)&Ws[8 + 2 * hs] = v;
            v.x = pkexp(d1s[12], d1s[13]); v.y = pkexp(d1s[14], d1s[15]);
            *(uint2*)&Ws[12 + 2 * hs] = v;
            v.x = pkexp(d1b[0], d1b[1]);  v.y = pkexp(d1b[2], d1b[3]);
            *(uint2*)&Wb[0 + 2 * hs] = v;
            v.x = pkexp(d1b[4], d1b[5]);  v.y = pkexp(d1b[6], d1b[7]);
            *(uint2*)&Wb[4 + 2 * hs] = v;
            v.x = pkexp(d1b[8], d1b[9]);  v.y = pkexp(d1b[10], d1b[11]);
            *(uint2*)&Wb[8 + 2 * hs] = v;
            v.x = pkexp(d1b[12], d1b[13]); v.y = pkexp(d1b[14], d1b[15]);
            *(uint2*)&Wb[12 + 2 * hs] = v;
        }
        // GEMM-2: out[i][c] += w[i][j] p[c][j], K=32 in one instr per (filter,isub)
        half8 A00 = rdfrag(R0s, quad);
        half8 A01 = rdfrag(R1s, quad);
        half8 A10 = rdfrag(R0b, quad);
        half8 A11 = rdfrag(R1b, quad);
        as0 = __builtin_amdgcn_mfma_f32_16x16x32_f16(A00, Bp, as0, 0, 0, 0);
        as1 = __builtin_amdgcn_mfma_f32_16x16x32_f16(A01, Bp, as1, 0, 0, 0);
        ab0 = __builtin_amdgcn_mfma_f32_16x16x32_f16(A10, Bp, ab0, 0, 0, 0);
        ab1 = __builtin_amdgcn_mfma_f32_16x16x32_f16(A11, Bp, ab1, 0, 0, 0);
    }

    // wt regions and rbuf regions overlap across waves -> barrier before overlay
    __syncthreads();

    // ---- cross-wave reduction in LDS (conflict-free dump: r*64+lane) ----
    {
        float* rb = sm.rbuf + w * 1024;
#pragma unroll
        for (int r = 0; r < 4; ++r) {
            rb[r * 64 + lane]       = as0[r];
            rb[256 + r * 64 + lane] = as1[r];
            rb[512 + r * 64 + lane] = ab0[r];
            rb[768 + r * 64 + lane] = ab1[r];
        }
    }
    __syncthreads();
    {
        float tot = 0.f;
#pragma unroll
        for (int w2 = 0; w2 < 16; ++w2) tot += sm.rbuf[w2 * 1024 + t];
        sm.rbuf[t] = tot;   // slot t read only by thread t (w2=0 term)
    }
    __syncthreads();

    // ---- combine + compatibility + softmax for this block's 32 i's ----
    if (t < IBLK) {
        int i = i0 + t;
        int sub = t >> 4, ql = (t & 15) >> 2, rr = t & 3;
        float sp[C], bl[C];
#pragma unroll
        for (int c = 0; c < C; ++c) {
            int base = sub * 256 + rr * 64 + ql * 16 + c;
            sp[c] = sm.rbuf[base];
            bl[c] = sm.rbuf[base + 512];
        }
        float msg[C];
#pragma unroll
        for (int c = 0; c < C; ++c) {
            float m = 0.f;
#pragma unroll
            for (int kk = 0; kk < C; ++kk)
                m += SW[c * C + kk] * sp[kk] + BW[c * C + kk] * bl[kk];
            msg[c] = m;
        }
        float qq[C];
#pragma unroll
        for (int c = 0; c < C; ++c) {
            float pw = 0.f;
#pragma unroll
            for (int kk = 0; kk < C; ++kk) pw += CM[c * C + kk] * msg[kk];
            qq[c] = unaries[c * N + i] - pw;
        }
        if (is_last) {
#pragma unroll
            for (int c = 0; c < C; ++c) out[c * N + i] = qq[c];
        } else {
            float m = qq[0];
#pragma unroll
            for (int c = 1; c < C; ++c) m = fmaxf(m, qq[c]);
            float e[C], s = 0.0f;
#pragma unroll
            for (int c = 0; c < C; ++c) {
                e[c] = __builtin_amdgcn_exp2f((qq[c] - m) * LOG2E);
                s += e[c];
            }
            float inv = 1.0f / s;
#pragma unroll
            for (int c = 0; c < C; ++c) pf_out[PFIDX(i, c)] = (_Float16)(e[c] * inv);
        }
    }
}

extern "C" void kernel_launch(void* const* d_in, const int* in_sizes, int n_in,
                              void* d_out, int out_size, void* d_ws, size_t ws_size,
                              hipStream_t stream) {
    const float* unaries = (const float*)d_in[0];   // [10, 8192]
    const float* feat    = (const float*)d_in[1];   // [6, 8192]
    const float* SW      = (const float*)d_in[2];   // [10,10]
    const float* BW      = (const float*)d_in[3];   // [10,10]
    const float* CM      = (const float*)d_in[4];   // [10,10]
    float* out = (float*)d_out;

    char* ws = (char*)d_ws;
    half8* ajs    = (half8*)(ws + WS_AJS);
    half8* ajb    = (half8*)(ws + WS_AJB);
    _Float16* pf0 = (_Float16*)(ws + WS_PF0);
    _Float16* pf1 = (_Float16*)(ws + WS_PF1);

    init_kernel<<<N / 256, 256, 0, stream>>>(unaries, feat, ajs, ajb, pf0, pf1);
    const _Float16* pin = pf0;
    _Float16* pout = pf1;
    for (int it = 1; it <= NUM_ITERS; ++it) {
        fused_kernel<<<NBLK, FBLOCK, 0, stream>>>(
            unaries, feat, SW, BW, CM, (const char*)ajs, (const char*)ajb,
            pin, pout, out, it == NUM_ITERS ? 1 : 0);
        const _Float16* tmp = pout;
        pout = (_Float16*)pin;
        pin = tmp;
    }
}

// Round 13
// 162.051 us; speedup vs baseline: 2.7925x; 1.0186x over previous
//
#include <hip/hip_runtime.h>
#include <math.h>

#define N 8192
#define C 10
#define NUM_ITERS 5
#define FBLOCK 1024        /* 16 waves, 1 block/CU, 4 waves/SIMD */
#define IBLK 32            /* i's per block */
#define NBLK (N / IBLK)    /* 256 blocks = 1 per CU */
#define JW (N / 16)        /* 512 j's per wave */
#define NS (JW / 32)       /* 16 s-iters per wave, 32 j's each */
#define LOG2E 1.44269504088896340736f
#define C3 (LOG2E / 64.0f)

typedef _Float16 half8 __attribute__((ext_vector_type(8)));
typedef _Float16 half4 __attribute__((ext_vector_type(4)));
typedef _Float16 half2 __attribute__((ext_vector_type(2)));
typedef float f32x4 __attribute__((ext_vector_type(4)));
typedef float f32x16 __attribute__((ext_vector_type(16)));

// ws layout:
//   ajs half8[N]          128KB : j-side spatial aug [f*C3 x3, 0 | 0,0,-h3*C3, 1]
//   ajb half8[N]          128KB : j-side bilateral aug [f*L2E x6 | -h6*L2E, 1]
//   pf0/pf1 f16[N/16][16][16]   : probs, J-TILED (tile jt, row c, col j&15)
#define WS_AJS 0
#define WS_AJB (N * 16)
#define WS_PF0 (N * 32)
#define WS_PF1 (N * 64)
#define PFIDX(n, c) ((((n) >> 4) * 16 + (c)) * 16 + ((n) & 15))

static __device__ __forceinline__ unsigned int pkexp(float a, float b) {
    float ea = __builtin_amdgcn_exp2f(a);
    float eb = __builtin_amdgcn_exp2f(b);
    return __builtin_bit_cast(unsigned int, __builtin_amdgcn_cvt_pkrtz(ea, eb));
}

// read one G2 A-fragment from the per-wave transpose tile:
// elems e0..3 = w[i][4q..4q+3] (u32 cols 2q,2q+1), e4..7 = w[i][16+4q..] (cols 8+2q,..)
static __device__ __forceinline__ half8 rdfrag(const unsigned int* R, int q) {
    uint2 lo = *(const uint2*)&R[2 * q];
    uint2 hi = *(const uint2*)&R[8 + 2 * q];
    half2 a = __builtin_bit_cast(half2, lo.x);
    half2 b = __builtin_bit_cast(half2, lo.y);
    half2 c = __builtin_bit_cast(half2, hi.x);
    half2 d = __builtin_bit_cast(half2, hi.y);
    half8 r = {a[0], a[1], b[0], b[1], c[0], c[1], d[0], d[1]};
    return r;
}

// once per launch: aug features + softmax(unaries) -> pf0 (tiled); zero rows 10..15 both
__global__ __launch_bounds__(256) void init_kernel(
    const float* __restrict__ unaries, const float* __restrict__ feat,
    half8* __restrict__ ajs8, half8* __restrict__ ajb8,
    _Float16* __restrict__ pf0, _Float16* __restrict__ pf1) {
    int n = blockIdx.x * 256 + threadIdx.x;
    float f6[6];
#pragma unroll
    for (int d = 0; d < 6; ++d) f6[d] = feat[d * N + n];
    float h3 = 0.5f * (f6[0] * f6[0] + f6[1] * f6[1] + f6[2] * f6[2]);
    float h6v = h3 + 0.5f * (f6[3] * f6[3] + f6[4] * f6[4] + f6[5] * f6[5]);
    half8 a = {};
    a[0] = (_Float16)(f6[0] * C3);
    a[1] = (_Float16)(f6[1] * C3);
    a[2] = (_Float16)(f6[2] * C3);
    a[6] = (_Float16)(-h3 * C3);
    a[7] = (_Float16)1.0f;
    ajs8[n] = a;
    half8 b;
#pragma unroll
    for (int d = 0; d < 6; ++d) b[d] = (_Float16)(f6[d] * LOG2E);
    b[6] = (_Float16)(-h6v * LOG2E);
    b[7] = (_Float16)1.0f;
    ajb8[n] = b;

    float q[C];
#pragma unroll
    for (int c = 0; c < C; ++c) q[c] = unaries[c * N + n];
    float m = q[0];
#pragma unroll
    for (int c = 1; c < C; ++c) m = fmaxf(m, q[c]);
    float e[C], s = 0.0f;
#pragma unroll
    for (int c = 0; c < C; ++c) {
        e[c] = __builtin_amdgcn_exp2f((q[c] - m) * LOG2E);
        s += e[c];
    }
    float inv = 1.0f / s;
#pragma unroll
    for (int c = 0; c < C; ++c) pf0[PFIDX(n, c)] = (_Float16)(e[c] * inv);
#pragma unroll
    for (int c = C; c < 16; ++c) {
        pf0[PFIDX(n, c)] = (_Float16)0.0f;
        pf1[PFIDX(n, c)] = (_Float16)0.0f;
    }
}

// one dispatch per CRF iteration. Block owns 32 i's; wave sweeps its 512-j slice.
// Per s-iter: GEMM1 = 2x mfma_32x32x16_f16; exp+cvt_pk -> per-wave LDS transpose
// tile; GEMM2 = 4x mfma_16x16x32_f16. NEW vs R12: (1) wave time-stagger via
// s_sleep breaks the cross-wave convoy (trans/MFMA/LDS phases of the 4 waves
// per SIMD now interleave instead of bursting in lockstep); (2) s_setprio(1)
// around MFMA clusters keeps the matrix pipe fed while other waves run exp/LDS.
__global__ __launch_bounds__(FBLOCK, 4) void fused_kernel(
    const float* __restrict__ unaries, const float* __restrict__ feat,
    const float* __restrict__ SW, const float* __restrict__ BW,
    const float* __restrict__ CM,
    const char* __restrict__ ajs_c, const char* __restrict__ ajb_c,
    const _Float16* __restrict__ pf_in, _Float16* __restrict__ pf_out,
    float* __restrict__ out, int is_last) {
    __shared__ union {
        unsigned int wt[16][2][32][18];   // 73,728 B: per-wave w-tiles (wave-private)
        float rbuf[16 * 1024];            // 64 KB epilogue reduction (after barrier)
    } sm;
    int t = threadIdx.x;
    int i0 = blockIdx.x * IBLK;
    int lane = t & 63;
    int w = t >> 6;
    int il = lane & 15;
    int quad = lane >> 4;
    int li = lane & 31;      // i (B1/G1-D col) or j (G1-A row) within 32
    int hs = lane >> 5;      // K-half select for 32x32x16 operands
    const f32x4 zero4 = {0.f, 0.f, 0.f, 0.f};
    const f32x16 zero16 = {};

    // ---- B1 fragments (G1 B-operand): lane holds aug[4hs..4hs+3] of i=i0+li ----
    half8 b1s, b1b;
    {
        int i = i0 + li;
        float g0 = feat[0 * N + i], g1 = feat[1 * N + i], g2 = feat[2 * N + i];
        float g3 = feat[3 * N + i], g4 = feat[4 * N + i], g5 = feat[5 * N + i];
        float h3 = 0.5f * (g0 * g0 + g1 * g1 + g2 * g2);
        float h6v = h3 + 0.5f * (g3 * g3 + g4 * g4 + g5 * g5);
        half4 slo = {(_Float16)g0, (_Float16)g1, (_Float16)g2, (_Float16)0.0f};
        half4 shi = {(_Float16)0.0f, (_Float16)0.0f, (_Float16)1.0f, (_Float16)(-h3 * C3)};
        half4 blo = {(_Float16)g0, (_Float16)g1, (_Float16)g2, (_Float16)g3};
        half4 bhi = {(_Float16)g4, (_Float16)g5, (_Float16)1.0f, (_Float16)(-h6v * LOG2E)};
        half4 sv = hs ? shi : slo;
        half4 bv = hs ? bhi : blo;
        half8 t1 = {sv[0], sv[1], sv[2], sv[3], (_Float16)0.0f, (_Float16)0.0f,
                    (_Float16)0.0f, (_Float16)0.0f};
        half8 t2 = {bv[0], bv[1], bv[2], bv[3], (_Float16)0.0f, (_Float16)0.0f,
                    (_Float16)0.0f, (_Float16)0.0f};
        b1s = t1;
        b1b = t2;
    }

    f32x4 as0 = zero4, as1 = zero4, ab0 = zero4, ab1 = zero4;
    int jw = w * JW;
    const half4* pfv = (const half4*)pf_in;
    unsigned int* Ws = &sm.wt[w][0][li][0];
    unsigned int* Wb = &sm.wt[w][1][li][0];
    const unsigned int* R0s = &sm.wt[w][0][il][0];
    const unsigned int* R1s = &sm.wt[w][0][16 + il][0];
    const unsigned int* R0b = &sm.wt[w][1][il][0];
    const unsigned int* R1b = &sm.wt[w][1][16 + il][0];

    // ---- convoy-breaking time stagger: offset the 4 waves/SIMD by ~128cy steps.
    // No sync points in the main loop -> the offset persists; w-tiles are
    // wave-private so desync is race-free.
    {
        int ph = w & 3;
        if (ph == 1) __builtin_amdgcn_s_sleep(2);
        else if (ph == 2) __builtin_amdgcn_s_sleep(4);
        else if (ph == 3) __builtin_amdgcn_s_sleep(6);
    }

    for (int k = 0; k < NS; ++k) {
        int j0 = jw + k * 32;
        half4 av_s = *(const half4*)(ajs_c + (size_t)(j0 + li) * 16 + hs * 8);
        half4 av_b = *(const half4*)(ajb_c + (size_t)(j0 + li) * 16 + hs * 8);
        half4 cp0 = pfv[((j0 >> 4) * 16 + il) * 4 + quad];
        half4 cp1 = pfv[(((j0 >> 4) + 1) * 16 + il) * 4 + quad];
        half8 A_s = {av_s[0], av_s[1], av_s[2], av_s[3], (_Float16)0.0f,
                     (_Float16)0.0f, (_Float16)0.0f, (_Float16)0.0f};
        half8 A_b = {av_b[0], av_b[1], av_b[2], av_b[3], (_Float16)0.0f,
                     (_Float16)0.0f, (_Float16)0.0f, (_Float16)0.0f};
        half8 Bp = {cp0[0], cp0[1], cp0[2], cp0[3], cp1[0], cp1[1], cp1[2], cp1[3]};

        // GEMM-1 cluster (prioritized)
        __builtin_amdgcn_s_setprio(1);
        f32x16 d1s = __builtin_amdgcn_mfma_f32_32x32x16_f16(A_s, b1s, zero16, 0, 0, 0);
        f32x16 d1b = __builtin_amdgcn_mfma_f32_32x32x16_f16(A_b, b1b, zero16, 0, 0, 0);
        __builtin_amdgcn_s_setprio(0);

        // exp2 + pack to f16-pairs (adjacent j) + transpose-store rows [i][j]
        {
            uint2 v;
            v.x = pkexp(d1s[0], d1s[1]);  v.y = pkexp(d1s[2], d1s[3]);
            *(uint2*)&Ws[0 + 2 * hs] = v;
            v.x = pkexp(d1s[4], d1s[5]);  v.y = pkexp(d1s[6], d1s[7]);
            *(uint2*)&Ws[4 + 2 * hs] = v;
            v.x = pkexp(d1s[8], d1s[9]);  v.y = pkexp(d1s[10], d1s[11]);
            *(uint2*)&Ws[8 + 2 * hs] = v;
            v.x = pkexp(d1s[12], d1s[13]); v.y = pkexp(d1s[14], d1s[15]);
            *(uint2*)&Ws[12 + 2 * hs] = v;
            v.x = pkexp(d1b[0], d1b[1]);  v.y = pkexp(d1b[2], d1b[3]);
            *(uint2*)&Wb[0 + 2 * hs] = v;
            v.x = pkexp(d1b[4], d1b[5]);  v.y = pkexp(d1b[6], d1b[7]);
            *(uint2*)&Wb[4 + 2 * hs] = v;
            v.x = pkexp(d1b[8], d1b[9]);  v.y = pkexp(d1b[10], d1b[11]);
            *(uint2*)&Wb[8 + 2 * hs] = v;
            v.x = pkexp(d1b[12], d1b[13]); v.y = pkexp(d1b[14], d1b[15]);
            *(uint2*)&Wb[12 + 2 * hs] = v;
        }
        // GEMM-2 cluster (prioritized)
        half8 A00 = rdfrag(R0s, quad);
        half8 A01 = rdfrag(R1s, quad);
        half8 A10 = rdfrag(R0b, quad);
        half8 A11 = rdfrag(R1b, quad);
        __builtin_amdgcn_s_setprio(1);
        as0 = __builtin_amdgcn_mfma_f32_16x16x32_f16(A00, Bp, as0, 0, 0, 0);
        as1 = __builtin_amdgcn_mfma_f32_16x16x32_f16(A01, Bp, as1, 0, 0, 0);
        ab0 = __builtin_amdgcn_mfma_f32_16x16x32_f16(A10, Bp, ab0, 0, 0, 0);
        ab1 = __builtin_amdgcn_mfma_f32_16x16x32_f16(A11, Bp, ab1, 0, 0, 0);
        __builtin_amdgcn_s_setprio(0);
    }

    // wt regions and rbuf regions overlap across waves -> barrier before overlay
    __syncthreads();

    // ---- cross-wave reduction in LDS (conflict-free dump: r*64+lane) ----
    {
        float* rb = sm.rbuf + w * 1024;
#pragma unroll
        for (int r = 0; r < 4; ++r) {
            rb[r * 64 + lane]       = as0[r];
            rb[256 + r * 64 + lane] = as1[r];
            rb[512 + r * 64 + lane] = ab0[r];
            rb[768 + r * 64 + lane] = ab1[r];
        }
    }
    __syncthreads();
    {
        float tot = 0.f;
#pragma unroll
        for (int w2 = 0; w2 < 16; ++w2) tot += sm.rbuf[w2 * 1024 + t];
        sm.rbuf[t] = tot;   // slot t read only by thread t (w2=0 term)
    }
    __syncthreads();

    // ---- combine + compatibility + softmax for this block's 32 i's ----
    if (t < IBLK) {
        int i = i0 + t;
        int sub = t >> 4, ql = (t & 15) >> 2, rr = t & 3;
        float sp[C], bl[C];
#pragma unroll
        for (int c = 0; c < C; ++c) {
            int base = sub * 256 + rr * 64 + ql * 16 + c;
            sp[c] = sm.rbuf[base];
            bl[c] = sm.rbuf[base + 512];
        }
        float msg[C];
#pragma unroll
        for (int c = 0; c < C; ++c) {
            float m = 0.f;
#pragma unroll
            for (int kk = 0; kk < C; ++kk)
                m += SW[c * C + kk] * sp[kk] + BW[c * C + kk] * bl[kk];
            msg[c] = m;
        }
        float qq[C];
#pragma unroll
        for (int c = 0; c < C; ++c) {
            float pw = 0.f;
#pragma unroll
            for (int kk = 0; kk < C; ++kk) pw += CM[c * C + kk] * msg[kk];
            qq[c] = unaries[c * N + i] - pw;
        }
        if (is_last) {
#pragma unroll
            for (int c = 0; c < C; ++c) out[c * N + i] = qq[c];
        } else {
            float m = qq[0];
#pragma unroll
            for (int c = 1; c < C; ++c) m = fmaxf(m, qq[c]);
            float e[C], s = 0.0f;
#pragma unroll
            for (int c = 0; c < C; ++c) {
                e[c] = __builtin_amdgcn_exp2f((qq[c] - m) * LOG2E);
                s += e[c];
            }
            float inv = 1.0f / s;
#pragma unroll
            for (int c = 0; c < C; ++c) pf_out[PFIDX(i, c)] = (_Float16)(e[c] * inv);
        }
    }
}

extern "C" void kernel_launch(void* const* d_in, const int* in_sizes, int n_in,
                              void* d_out, int out_size, void* d_ws, size_t ws_size,
                              hipStream_t stream) {
    const float* unaries = (const float*)d_in[0];   // [10, 8192]
    const float* feat    = (const float*)d_in[1];   // [6, 8192]
    const float* SW      = (const float*)d_in[2];   // [10,10]
    const float* BW      = (const float*)d_in[3];   // [10,10]
    const float* CM      = (const float*)d_in[4];   // [10,10]
    float* out = (float*)d_out;

    char* ws = (char*)d_ws;
    half8* ajs    = (half8*)(ws + WS_AJS);
    half8* ajb    = (half8*)(ws + WS_AJB);
    _Float16* pf0 = (_Float16*)(ws + WS_PF0);
    _Float16* pf1 = (_Float16*)(ws + WS_PF1);

    init_kernel<<<N / 256, 256, 0, stream>>>(unaries, feat, ajs, ajb, pf0, pf1);
    const _Float16* pin = pf0;
    _Float16* pout = pf1;
    for (int it = 1; it <= NUM_ITERS; ++it) {
        fused_kernel<<<NBLK, FBLOCK, 0, stream>>>(
            unaries, feat, SW, BW, CM, (const char*)ajs, (const char*)ajb,
            pin, pout, out, it == NUM_ITERS ? 1 : 0);
        const _Float16* tmp = pout;
        pout = (_Float16*)pin;
        pin = tmp;
    }
}